// Round 9
// baseline (77.322 us; speedup 1.0000x reference)
//
#include <hip/hip_runtime.h>
#include <stdint.h>

typedef short bf16x8 __attribute__((ext_vector_type(8)));
typedef float f32x4 __attribute__((ext_vector_type(4)));

__device__ __forceinline__ unsigned short f2bf(float f) {
  unsigned u = __float_as_uint(f);
  u += 0x7fffu + ((u >> 16) & 1u);   // RNE round to bf16
  return (unsigned short)(u >> 16);
}
__device__ __forceinline__ unsigned umax_(unsigned a, unsigned b) { return a > b ? a : b; }

// ---- prep: emb fp32 -> fragment-tiled bf16 embb, h2s = 0.5*||e||^2 + 1 ----
// per 16-emb tile (8KB): byte = (n>>4)*8192 + (c8*16 + (n&15))*16, c8 = c/8
__global__ __launch_bounds__(256) void k_prep(const float* __restrict__ emb,
                                              unsigned short* __restrict__ embb,
                                              float* __restrict__ h2s) {
  const int t = threadIdx.x;
  const int n = blockIdx.x * 8 + (t >> 5);
  const int c8 = t & 31;
  const float* src = emb + (size_t)n * 256 + c8 * 8;
  float s = 0.f;
  union { bf16x8 v; unsigned short u[8]; } pk;
#pragma unroll
  for (int i = 0; i < 8; ++i) {
    float f = src[i];
    s += f * f;
    pk.u[i] = f2bf(f);
  }
  *(bf16x8*)((char*)embb + (size_t)(n >> 4) * 8192 + (c8 * 16 + (n & 15)) * 16) = pk.v;
#pragma unroll
  for (int m = 1; m < 32; m <<= 1) s += __shfl_xor(s, m);
  if ((t & 31) == 0) h2s[n] = 0.5f * s + 1.0f;   // +1 keeps scores strictly < 0
}

// ---- fused: A(32 rows/wave) in regs, B streamed global->register ring.
// Block = 64 rows x 1024 embs; waves (wm x wn) = rows x emb-half. No hot-loop LDS.
__global__ __launch_bounds__(256, 3) void k_fused(
    const float* __restrict__ z, const float* __restrict__ emb,
    const unsigned short* __restrict__ embb, const float* __restrict__ h2s,
    float* __restrict__ out, float* __restrict__ acc_g,
    unsigned* __restrict__ done, float* __restrict__ lossp) {

  __shared__ __align__(16) char Lmem[33280];   // A-tile 32KB; epi float[128][65]
  __shared__ __align__(16) float hL[1024];
  __shared__ unsigned kbuf[2][64];
  __shared__ float red[4];
  __shared__ int sidx[64];

  const int t = threadIdx.x;
  const int lane = t & 63;
  const int w = t >> 6;
  const int wm = w >> 1, wn = w & 1;
  const int l15 = lane & 15;
  const int l4 = lane >> 4;
  const int b = blockIdx.x >> 4;
  const int hw0 = (blockIdx.x & 15) * 64;

  // ---- phase A: z -> LDS A-tile (fragment layout), sumsq; h2s -> hL
  {
    const int hw = t & 63, cg = t >> 6;
    const float* zp = z + (size_t)b * 262144 + hw0 + hw;
    float ss = 0.f;
#pragma unroll
    for (int i = 0; i < 8; ++i) {
      const int c8 = i * 4 + cg;
      union { bf16x8 v; unsigned short u[8]; } pk;
#pragma unroll
      for (int j = 0; j < 8; ++j) {
        const float f = zp[(size_t)(c8 * 8 + j) * 1024];
        ss += f * f;
        pk.u[j] = f2bf(f);
      }
      *(bf16x8*)(Lmem + (hw >> 4) * 8192 + (c8 * 16 + (hw & 15)) * 16) = pk.v;
    }
    ((float4*)hL)[t] = *(const float4*)(h2s + t * 4);
#pragma unroll
    for (int m = 1; m < 64; m <<= 1) ss += __shfl_xor(ss, m);
    if (lane == 0) red[w] = ss;
  }
  __syncthreads();

  // ---- A-frags -> regs: wave's 32 rows = tiles wm*2, wm*2+1
  bf16x8 af[2][8];
#pragma unroll
  for (int ti = 0; ti < 2; ++ti)
#pragma unroll
    for (int kk = 0; kk < 8; ++kk)
      af[ti][kk] = *(const bf16x8*)(Lmem + (wm * 2 + ti) * 8192 + kk * 1024 + l4 * 256 + l15 * 16);
  __syncthreads();   // Lmem dead until epilogue

  // ---- hot loop: 32 tiles of 16 embs (wave's 512-emb half), B->reg ring
  const char* Bb = (const char*)embb + (size_t)wn * 262144 + l4 * 256 + l15 * 16;
  const float* hb = hL + wn * 512 + l15;
  unsigned kb[2][4];
#pragma unroll
  for (int mi = 0; mi < 2; ++mi)
#pragma unroll
    for (int j = 0; j < 4; ++j) kb[mi][j] = 0u;
  const unsigned ciob = (unsigned)(1023 - wn * 512 - l15);

  bf16x8 bA[8], bB[8];
#pragma unroll
  for (int kk = 0; kk < 8; ++kk) bA[kk] = *(const bf16x8*)(Bb + kk * 1024);

#define MFMA_FOLD(BUF, TL)                                                          \
  {                                                                                 \
    f32x4 a0{}, a1{};                                                               \
    _Pragma("unroll")                                                               \
    for (int kk = 0; kk < 8; ++kk) {                                                \
      a0 = __builtin_amdgcn_mfma_f32_16x16x32_bf16(af[0][kk], BUF[kk], a0, 0, 0, 0);\
      a1 = __builtin_amdgcn_mfma_f32_16x16x32_bf16(af[1][kk], BUF[kk], a1, 0, 0, 0);\
    }                                                                               \
    const float hv = hb[(TL) * 16];                                                 \
    const unsigned cio = ciob - (TL) * 16;                                          \
    _Pragma("unroll")                                                               \
    for (int j = 0; j < 4; ++j) {                                                   \
      const float v0 = a0[j] - hv;                                                  \
      const float v1 = a1[j] - hv;                                                  \
      kb[0][j] = umax_(kb[0][j], (~__float_as_uint(v0) & 0xFFFFFC00u) | cio);       \
      kb[1][j] = umax_(kb[1][j], (~__float_as_uint(v1) & 0xFFFFFC00u) | cio);       \
    }                                                                               \
  }

  for (int t2 = 0; t2 < 16; ++t2) {
    const int tl = t2 * 2;
#pragma unroll
    for (int kk = 0; kk < 8; ++kk)
      bB[kk] = *(const bf16x8*)(Bb + (size_t)(tl + 1) * 8192 + kk * 1024);
    MFMA_FOLD(bA, tl)
    if (t2 < 15) {
#pragma unroll
      for (int kk = 0; kk < 8; ++kk)
        bA[kk] = *(const bf16x8*)(Bb + (size_t)(tl + 2) * 8192 + kk * 1024);
    }
    MFMA_FOLD(bB, tl + 1)
  }
#undef MFMA_FOLD

  // ---- per-wave 16-lane DPP key-max, merge wn pair, loss partial
#pragma unroll
  for (int mi = 0; mi < 2; ++mi)
#pragma unroll
    for (int j = 0; j < 4; ++j) {
      unsigned k = kb[mi][j];
      k = umax_(k, (unsigned)__builtin_amdgcn_update_dpp(0, (int)k, 0xB1, 0xF, 0xF, true));
      k = umax_(k, (unsigned)__builtin_amdgcn_update_dpp(0, (int)k, 0x4E, 0xF, 0xF, true));
      k = umax_(k, (unsigned)__builtin_amdgcn_update_dpp(0, (int)k, 0x141, 0xF, 0xF, true));
      k = umax_(k, (unsigned)__builtin_amdgcn_update_dpp(0, (int)k, 0x140, 0xF, 0xF, true));
      if (l15 == 0) kbuf[wn][wm * 32 + mi * 16 + l4 * 4 + j] = k;
    }
  __syncthreads();
  if (t < 64) {
    const unsigned k = umax_(kbuf[0][t], kbuf[1][t]);
    sidx[t] = 1023 - (int)(k & 1023u);
    float s = __uint_as_float(~k) + 1.0f;   // t* = x.e - 0.5||e||^2
#pragma unroll
    for (int m = 1; m < 64; m <<= 1) s += __shfl_xor(s, m);
    if (t == 0) atomicAdd(acc_g, red[0] + red[1] + red[2] + red[3] - 2.f * s);
  }
  __syncthreads();

  // ---- epilogue: 2 passes of 128 c; gather -> LDS [c][hw] (stride 65) -> out
  float* fst = (float*)Lmem;
  float* ob = out + (size_t)b * 262144 + hw0;
  const int hwR = t >> 2, cq = t & 3;
  const float* ep = emb + (size_t)sidx[hwR] * 256;
#pragma unroll
  for (int p = 0; p < 2; ++p) {
#pragma unroll
    for (int s4 = 0; s4 < 2; ++s4)
#pragma unroll
      for (int f = 0; f < 4; ++f) {
        const int cl = s4 * 64 + cq * 16 + f * 4;
        const float4 v = *(const float4*)(ep + p * 128 + cl);
        fst[(cl + 0) * 65 + hwR] = v.x;
        fst[(cl + 1) * 65 + hwR] = v.y;
        fst[(cl + 2) * 65 + hwR] = v.z;
        fst[(cl + 3) * 65 + hwR] = v.w;
      }
    __syncthreads();
#pragma unroll
    for (int i = 0; i < 8; ++i) {
      const int cl = i * 16 + (t >> 4);
      const float4 vv = *(const float4*)(fst + cl * 65 + (t & 15) * 4);
      *(float4*)(ob + (size_t)(p * 128 + cl) * 1024 + (t & 15) * 4) = vv;
    }
    __syncthreads();
  }

  if (t == 0) {
    __threadfence();
    const unsigned old = atomicAdd(done, 1u);
    if (old == 511u) {
      const float tot = atomicAdd(acc_g, 0.f);
      lossp[0] = 1.25f * tot * (1.0f / 8388608.0f);
    }
  }
}

extern "C" void kernel_launch(void* const* d_in, const int* in_sizes, int n_in,
                              void* d_out, int out_size, void* d_ws, size_t ws_size,
                              hipStream_t stream) {
  (void)in_sizes; (void)n_in; (void)ws_size;
  const float* z   = (const float*)d_in[0];
  const float* emb = (const float*)d_in[1];
  float* out = (float*)d_out;
  char* ws = (char*)d_ws;
  unsigned short* embb = (unsigned short*)ws;       // 512 KB (fragment-tiled)
  float* h2s   = (float*)(ws + 524288);             // 4 KB
  float* acc   = (float*)(ws + 528384);             // 4 B
  unsigned* done = (unsigned*)(ws + 528388);        // 4 B

  hipMemsetAsync(ws + 528384, 0, 8, stream);
  hipLaunchKernelGGL(k_prep, dim3(128), dim3(256), 0, stream, emb, embb, h2s);
  hipLaunchKernelGGL(k_fused, dim3(512), dim3(256), 0, stream, z, emb, embb, h2s,
                     out, acc, done, out + (size_t)out_size - 1);
}

// Round 10
// 73.784 us; speedup vs baseline: 1.0480x; 1.0480x over previous
//
#include <hip/hip_runtime.h>
#include <stdint.h>

typedef short bf16x8 __attribute__((ext_vector_type(8)));
typedef float f32x4 __attribute__((ext_vector_type(4)));

__device__ __forceinline__ unsigned short f2bf(float f) {
  unsigned u = __float_as_uint(f);
  u += 0x7fffu + ((u >> 16) & 1u);   // RNE round to bf16
  return (unsigned short)(u >> 16);
}
__device__ __forceinline__ unsigned umax_(unsigned a, unsigned b) { return a > b ? a : b; }

// ---- prep: emb fp32 -> fragment-tiled bf16 embb, h2s = 0.5*||e||^2 + 1 ----
// per 16-emb tile (8KB): byte = (n>>4)*8192 + (c8*16 + (n&15))*16, c8 = c/8
__global__ __launch_bounds__(256) void k_prep(const float* __restrict__ emb,
                                              unsigned short* __restrict__ embb,
                                              float* __restrict__ h2s) {
  const int t = threadIdx.x;
  const int n = blockIdx.x * 8 + (t >> 5);
  const int c8 = t & 31;
  const float* src = emb + (size_t)n * 256 + c8 * 8;
  float s = 0.f;
  union { bf16x8 v; unsigned short u[8]; } pk;
#pragma unroll
  for (int i = 0; i < 8; ++i) {
    float f = src[i];
    s += f * f;
    pk.u[i] = f2bf(f);
  }
  *(bf16x8*)((char*)embb + (size_t)(n >> 4) * 8192 + (c8 * 16 + (n & 15)) * 16) = pk.v;
#pragma unroll
  for (int m = 1; m < 32; m <<= 1) s += __shfl_xor(s, m);
  if ((t & 31) == 0) h2s[n] = 0.5f * s + 1.0f;   // +1 keeps scores strictly < 0
}

// ---- fused: wave = 16 rows x ALL 1024 embs. A truly in regs (af[8]=32 VGPR).
// All 4 waves share the same B stream (L1-friendly). No hot-loop LDS/barriers.
__global__ __launch_bounds__(256, 2) void k_fused(
    const float* __restrict__ z, const float* __restrict__ emb,
    const unsigned short* __restrict__ embb, const float* __restrict__ h2s,
    float* __restrict__ out, float* __restrict__ acc_g,
    unsigned* __restrict__ done, float* __restrict__ lossp) {

  __shared__ __align__(16) char Lmem[33280];   // A-tile 32KB; epi float[128][65]
  __shared__ __align__(16) float hL[1024];
  __shared__ unsigned kbuf[64];
  __shared__ float red[4];
  __shared__ int sidx[64];

  const int t = threadIdx.x;
  const int lane = t & 63;
  const int w = t >> 6;
  const int l15 = lane & 15;
  const int l4 = lane >> 4;
  const int b = blockIdx.x >> 4;
  const int hw0 = (blockIdx.x & 15) * 64;

  // ---- phase A: z -> LDS A-tile (fragment layout), sumsq; h2s -> hL
  {
    const int hw = t & 63, cg = t >> 6;
    const float* zp = z + (size_t)b * 262144 + hw0 + hw;
    float ss = 0.f;
#pragma unroll
    for (int i = 0; i < 8; ++i) {
      const int c8 = i * 4 + cg;
      union { bf16x8 v; unsigned short u[8]; } pk;
#pragma unroll
      for (int j = 0; j < 8; ++j) {
        const float f = zp[(size_t)(c8 * 8 + j) * 1024];
        ss += f * f;
        pk.u[j] = f2bf(f);
      }
      *(bf16x8*)(Lmem + (hw >> 4) * 8192 + (c8 * 16 + (hw & 15)) * 16) = pk.v;
    }
    ((float4*)hL)[t] = *(const float4*)(h2s + t * 4);
#pragma unroll
    for (int m = 1; m < 64; m <<= 1) ss += __shfl_xor(ss, m);
    if (lane == 0) red[w] = ss;
  }
  __syncthreads();

  // ---- A-frags -> regs: wave w owns rows [w*16, w*16+16) -> af[8] = 32 VGPR
  bf16x8 af[8];
#pragma unroll
  for (int kk = 0; kk < 8; ++kk)
    af[kk] = *(const bf16x8*)(Lmem + w * 8192 + kk * 1024 + l4 * 256 + l15 * 16);
  __syncthreads();   // Lmem dead until epilogue

  // ---- hot loop: 64 tiles of 16 embs (shared across waves), B->reg ring
  const char* Bb = (const char*)embb + l4 * 256 + l15 * 16;
  unsigned kb[4] = {0u, 0u, 0u, 0u};

  bf16x8 bA[8], bB[8];
#pragma unroll
  for (int kk = 0; kk < 8; ++kk) bA[kk] = *(const bf16x8*)(Bb + kk * 1024);

#define MFMA_FOLD(BUF, TL)                                                           \
  {                                                                                  \
    f32x4 aLo{}, aHi{};                                                              \
    aLo = __builtin_amdgcn_mfma_f32_16x16x32_bf16(af[0], BUF[0], aLo, 0, 0, 0);      \
    aHi = __builtin_amdgcn_mfma_f32_16x16x32_bf16(af[4], BUF[4], aHi, 0, 0, 0);      \
    aLo = __builtin_amdgcn_mfma_f32_16x16x32_bf16(af[1], BUF[1], aLo, 0, 0, 0);      \
    aHi = __builtin_amdgcn_mfma_f32_16x16x32_bf16(af[5], BUF[5], aHi, 0, 0, 0);      \
    aLo = __builtin_amdgcn_mfma_f32_16x16x32_bf16(af[2], BUF[2], aLo, 0, 0, 0);      \
    aHi = __builtin_amdgcn_mfma_f32_16x16x32_bf16(af[6], BUF[6], aHi, 0, 0, 0);      \
    aLo = __builtin_amdgcn_mfma_f32_16x16x32_bf16(af[3], BUF[3], aLo, 0, 0, 0);      \
    aHi = __builtin_amdgcn_mfma_f32_16x16x32_bf16(af[7], BUF[7], aHi, 0, 0, 0);      \
    const float hv = hL[(TL) * 16 + l15];                                            \
    const unsigned cio = (unsigned)(1023 - ((TL) * 16 + l15));                       \
    _Pragma("unroll")                                                                \
    for (int j = 0; j < 4; ++j) {                                                    \
      const float v = (aLo[j] + aHi[j]) - hv;                                        \
      kb[j] = umax_(kb[j], (~__float_as_uint(v) & 0xFFFFFC00u) | cio);               \
    }                                                                                \
  }

  for (int t2 = 0; t2 < 32; ++t2) {
    const int tl = t2 * 2;
#pragma unroll
    for (int kk = 0; kk < 8; ++kk)
      bB[kk] = *(const bf16x8*)(Bb + (size_t)(tl + 1) * 8192 + kk * 1024);
    MFMA_FOLD(bA, tl)
    if (t2 < 31) {
#pragma unroll
      for (int kk = 0; kk < 8; ++kk)
        bA[kk] = *(const bf16x8*)(Bb + (size_t)(tl + 2) * 8192 + kk * 1024);
    }
    MFMA_FOLD(bB, tl + 1)
  }
#undef MFMA_FOLD

  // ---- 16-lane DPP key-max; each row owned by exactly one wave
#pragma unroll
  for (int j = 0; j < 4; ++j) {
    unsigned k = kb[j];
    k = umax_(k, (unsigned)__builtin_amdgcn_update_dpp(0, (int)k, 0xB1, 0xF, 0xF, true));
    k = umax_(k, (unsigned)__builtin_amdgcn_update_dpp(0, (int)k, 0x4E, 0xF, 0xF, true));
    k = umax_(k, (unsigned)__builtin_amdgcn_update_dpp(0, (int)k, 0x141, 0xF, 0xF, true));
    k = umax_(k, (unsigned)__builtin_amdgcn_update_dpp(0, (int)k, 0x140, 0xF, 0xF, true));
    if (l15 == 0) kbuf[w * 16 + l4 * 4 + j] = k;
  }
  __syncthreads();

  // ---- decode, loss partial
  if (t < 64) {
    const unsigned k = kbuf[t];
    sidx[t] = 1023 - (int)(k & 1023u);
    float s = __uint_as_float(~k) + 1.0f;   // t* = x.e - 0.5||e||^2
#pragma unroll
    for (int m = 1; m < 64; m <<= 1) s += __shfl_xor(s, m);
    if (t == 0) atomicAdd(acc_g, red[0] + red[1] + red[2] + red[3] - 2.f * s);
  }
  __syncthreads();

  // ---- epilogue: 2 passes of 128 c; gather -> LDS [c][hw] (stride 65) -> out
  float* fst = (float*)Lmem;
  float* ob = out + (size_t)b * 262144 + hw0;
  const int hwR = t >> 2, cq = t & 3;
  const float* ep = emb + (size_t)sidx[hwR] * 256;
#pragma unroll
  for (int p = 0; p < 2; ++p) {
#pragma unroll
    for (int s4 = 0; s4 < 2; ++s4)
#pragma unroll
      for (int f = 0; f < 4; ++f) {
        const int cl = s4 * 64 + cq * 16 + f * 4;
        const float4 v = *(const float4*)(ep + p * 128 + cl);
        fst[(cl + 0) * 65 + hwR] = v.x;
        fst[(cl + 1) * 65 + hwR] = v.y;
        fst[(cl + 2) * 65 + hwR] = v.z;
        fst[(cl + 3) * 65 + hwR] = v.w;
      }
    __syncthreads();
#pragma unroll
    for (int i = 0; i < 8; ++i) {
      const int cl = i * 16 + (t >> 4);
      const float4 vv = *(const float4*)(fst + cl * 65 + (t & 15) * 4);
      *(float4*)(ob + (size_t)(p * 128 + cl) * 1024 + (t & 15) * 4) = vv;
    }
    __syncthreads();
  }

  if (t == 0) {
    __threadfence();
    const unsigned old = atomicAdd(done, 1u);
    if (old == 511u) {
      const float tot = atomicAdd(acc_g, 0.f);
      lossp[0] = 1.25f * tot * (1.0f / 8388608.0f);
    }
  }
}

extern "C" void kernel_launch(void* const* d_in, const int* in_sizes, int n_in,
                              void* d_out, int out_size, void* d_ws, size_t ws_size,
                              hipStream_t stream) {
  (void)in_sizes; (void)n_in; (void)ws_size;
  const float* z   = (const float*)d_in[0];
  const float* emb = (const float*)d_in[1];
  float* out = (float*)d_out;
  char* ws = (char*)d_ws;
  unsigned short* embb = (unsigned short*)ws;       // 512 KB (fragment-tiled)
  float* h2s   = (float*)(ws + 524288);             // 4 KB
  float* acc   = (float*)(ws + 528384);             // 4 B
  unsigned* done = (unsigned*)(ws + 528388);        // 4 B

  hipMemsetAsync(ws + 528384, 0, 8, stream);
  hipLaunchKernelGGL(k_prep, dim3(128), dim3(256), 0, stream, emb, embb, h2s);
  hipLaunchKernelGGL(k_fused, dim3(512), dim3(256), 0, stream, z, emb, embb, h2s,
                     out, acc, done, out + (size_t)out_size - 1);
}